// Round 1
// baseline (436.415 us; speedup 1.0000x reference)
//
#include <hip/hip_runtime.h>

// Problem constants (from reference): N_T=5, 32x32 grid, N=1024, batch=4.
#define NT   5
#define NY   32
#define NX   32
#define NN   1024          // N = NY*NX
#define QDIM 5120          // NT * NN
#define NB   4

// Compute the 9 stencil coefficients of M = I + A for node n at time t, batch b.
// Offsets (oy,ox): 0:(0,0) 1:(0,1) 2:(0,-1) 3:(1,0) 4:(-1,0) 5:(1,1) 6:(1,-1) 7:(-1,1) 8:(-1,-1)
// Invalid (out-of-grid) neighbor coefficients are zeroed, matching VALID in the reference.
__device__ __forceinline__ void stencil9(const float* __restrict__ kap,
                                         const float* __restrict__ m,
                                         const float* __restrict__ H,
                                         int b, int t, int n, float s[9]) {
    // Input layouts (row-major):
    //   kappa: (NB, 1, NN, NT)
    //   m:     (NB, 2, NN, NT)
    //   H:     (NB, 2, 2, NN, NT)
    float k   = kap[((size_t)b * NN + n) * NT + t];
    float mx  = m[(((size_t)b * 2 + 0) * NN + n) * NT + t];
    float my  = m[(((size_t)b * 2 + 1) * NN + n) * NT + t];
    float H11 = H[((((size_t)b * 2 + 0) * 2 + 0) * NN + n) * NT + t];
    float H01 = H[((((size_t)b * 2 + 0) * 2 + 1) * NN + n) * NT + t];
    float H10 = H[((((size_t)b * 2 + 1) * 2 + 0) * NN + n) * NT + t];
    float H22 = H[((((size_t)b * 2 + 1) * 2 + 1) * NN + n) * NT + t];
    // DX=DY=DT=1
    float cc = 0.25f * (H01 + H10);           // H12/(2*DX*DY) with H12 = 0.5*(H01+H10)
    s[0] = 1.0f + k * k + 2.0f * H11 + 2.0f * H22;   // diagonal of M = 1 + c0
    s[1] =  0.5f * mx - H11;    // (0,+1)
    s[2] = -0.5f * mx - H11;    // (0,-1)
    s[3] =  0.5f * my - H22;    // (+1,0)
    s[4] = -0.5f * my - H22;    // (-1,0)
    s[5] = -cc;                 // (+1,+1)
    s[6] =  cc;                 // (+1,-1)
    s[7] =  cc;                 // (-1,+1)
    s[8] = -cc;                 // (-1,-1)
    int y = n >> 5, x = n & 31;
    if (x == NX - 1) { s[1] = 0.f; s[5] = 0.f; s[7] = 0.f; }
    if (x == 0)      { s[2] = 0.f; s[6] = 0.f; s[8] = 0.f; }
    if (y == NY - 1) { s[3] = 0.f; s[5] = 0.f; s[6] = 0.f; }
    if (y == 0)      { s[4] = 0.f; s[7] = 0.f; s[8] = 0.f; }
}

// One thread per (b, t, node r). Computes row r of MM = M*M (5x5 stencil) and
// scatters the nonzero entries of Q (memset to zero beforehand):
//   diag block (t,t):   MM[t] (+I for interior t)
//   block (t+1, t):     -M[t]   (sub-diagonal, t <= NT-2)
//   block (t-1, t):     -M[t]   (super-diagonal, t >= 1)
__global__ __launch_bounds__(256) void spde_scatter(const float* __restrict__ kap,
                                                    const float* __restrict__ m,
                                                    const float* __restrict__ H,
                                                    float* __restrict__ Q) {
    int tid = blockIdx.x * blockDim.x + threadIdx.x;
    if (tid >= NB * NT * NN) return;
    int r  = tid & (NN - 1);
    int bt = tid >> 10;
    int t  = bt % NT;
    int b  = bt / NT;

    const int oy[9] = {0, 0, 0, 1, -1, 1, 1, -1, -1};
    const int ox[9] = {0, 1, -1, 0, 0, 1, -1, 1, -1};

    float sr[9];
    stencil9(kap, m, H, b, t, r, sr);
    int ry = r >> 5, rx = r & 31;

    // 5x5 accumulator for row r of MM, indexed by (dy+2, dx+2), dy,dx in [-2,2]
    float acc[5][5];
#pragma unroll
    for (int i = 0; i < 5; ++i)
#pragma unroll
        for (int j = 0; j < 5; ++j) acc[i][j] = 0.f;

#pragma unroll
    for (int d1 = 0; d1 < 9; ++d1) {
        float a = sr[d1];                    // == 0 for invalid neighbor (zeroed above)
        int ky = ry + oy[d1], kx = rx + ox[d1];
        bool valid = ((unsigned)ky < NY) && ((unsigned)kx < NX);
        int k = valid ? (ky * NX + kx) : r;  // clamp like the reference; a==0 kills it
        float sk[9];
        stencil9(kap, m, H, b, t, k, sk);
#pragma unroll
        for (int d2 = 0; d2 < 9; ++d2) {
            acc[oy[d1] + oy[d2] + 2][ox[d1] + ox[d2] + 2] += a * sk[d2];
        }
    }
    // MM + I for interior time blocks (1 <= t <= NT-2)
    if (t >= 1 && t <= NT - 2) acc[2][2] += 1.0f;

    size_t brow = (size_t)b * QDIM * QDIM;

    // Diagonal block (t, t): write the valid 5x5 tile of row r
    {
        size_t rowoff = brow + (size_t)(t * NN + r) * QDIM + (size_t)t * NN;
#pragma unroll
        for (int dy = -2; dy <= 2; ++dy) {
            int cy = ry + dy;
            if ((unsigned)cy >= NY) continue;
#pragma unroll
            for (int dx = -2; dx <= 2; ++dx) {
                int cx = rx + dx;
                if ((unsigned)cx >= NX) continue;
                Q[rowoff + cy * NX + cx] = acc[dy + 2][dx + 2];
            }
        }
    }

    // Off-diagonal blocks: -M[t] at (t-1, t) and (t+1, t), column-block t
#pragma unroll
    for (int d = 0; d < 9; ++d) {
        int cy = ry + oy[d], cx = rx + ox[d];
        if ((unsigned)cy >= NY || (unsigned)cx >= NX) continue;
        int c = cy * NX + cx;
        float v = -sr[d];
        if (t >= 1)
            Q[brow + (size_t)((t - 1) * NN + r) * QDIM + (size_t)t * NN + c] = v;
        if (t <= NT - 2)
            Q[brow + (size_t)((t + 1) * NN + r) * QDIM + (size_t)t * NN + c] = v;
    }
}

extern "C" void kernel_launch(void* const* d_in, const int* in_sizes, int n_in,
                              void* d_out, int out_size, void* d_ws, size_t ws_size,
                              hipStream_t stream) {
    const float* kap = (const float*)d_in[0];
    const float* m   = (const float*)d_in[1];
    const float* H   = (const float*)d_in[2];
    float* Q = (float*)d_out;

    // Zero the whole output (it is poisoned before every timed launch).
    hipMemsetAsync(d_out, 0, (size_t)out_size * sizeof(float), stream);

    int total = NB * NT * NN;  // 20480
    spde_scatter<<<(total + 255) / 256, 256, 0, stream>>>(kap, m, H, Q);
}

// Round 2
// 417.555 us; speedup vs baseline: 1.0452x; 1.0452x over previous
//
#include <hip/hip_runtime.h>

// Problem constants (from reference): N_T=5, 32x32 grid, N=1024, batch=4.
#define NT   5
#define NY   32
#define NX   32
#define NN   1024          // N = NY*NX
#define QDIM 5120          // NT * NN
#define NB   4

// Canonical stencil offset order (matches reference's offs list):
// 0:(0,0) 1:(0,1) 2:(0,-1) 3:(1,0) 4:(-1,0) 5:(1,1) 6:(1,-1) 7:(-1,1) 8:(-1,-1)
__device__ const int c_oy[9] = {0, 0, 0, 1, -1, 1, 1, -1, -1};
__device__ const int c_ox[9] = {0, 1, -1, 0, 0, 1, -1, 1, -1};

// Stencil coefficients of M = I + A for node n, time t, batch b.
// Out-of-grid neighbor coefficients zeroed (matches VALID in reference).
__device__ __forceinline__ void stencil9(const float* __restrict__ kap,
                                         const float* __restrict__ m,
                                         const float* __restrict__ H,
                                         int b, int t, int n, float s[9]) {
    // Layouts: kappa (NB,1,NN,NT); m (NB,2,NN,NT); H (NB,2,2,NN,NT)
    float k   = kap[((size_t)b * NN + n) * NT + t];
    float mx  = m[(((size_t)b * 2 + 0) * NN + n) * NT + t];
    float my  = m[(((size_t)b * 2 + 1) * NN + n) * NT + t];
    float H11 = H[((((size_t)b * 2 + 0) * 2 + 0) * NN + n) * NT + t];
    float H01 = H[((((size_t)b * 2 + 0) * 2 + 1) * NN + n) * NT + t];
    float H10 = H[((((size_t)b * 2 + 1) * 2 + 0) * NN + n) * NT + t];
    float H22 = H[((((size_t)b * 2 + 1) * 2 + 1) * NN + n) * NT + t];
    float cc = 0.25f * (H01 + H10);                  // H12/(2 DX DY), DX=DY=1
    s[0] = 1.0f + k * k + 2.0f * H11 + 2.0f * H22;   // diag of M = 1 + c0
    s[1] =  0.5f * mx - H11;    // (0,+1)
    s[2] = -0.5f * mx - H11;    // (0,-1)
    s[3] =  0.5f * my - H22;    // (+1,0)
    s[4] = -0.5f * my - H22;    // (-1,0)
    s[5] = -cc;                 // (+1,+1)
    s[6] =  cc;                 // (+1,-1)
    s[7] =  cc;                 // (-1,+1)
    s[8] = -cc;                 // (-1,-1)
    int y = n >> 5, x = n & 31;
    if (x == NX - 1) { s[1] = 0.f; s[5] = 0.f; s[7] = 0.f; }
    if (x == 0)      { s[2] = 0.f; s[6] = 0.f; s[8] = 0.f; }
    if (y == NY - 1) { s[3] = 0.f; s[5] = 0.f; s[6] = 0.f; }
    if (y == 0)      { s[4] = 0.f; s[7] = 0.f; s[8] = 0.f; }
}

// One workgroup per output row (b, g = t*NN + r). Prologue computes the row's
// nonzero values into LDS; then all 256 threads stream the full 5120-column
// row with coalesced float4 stores (value where structured-nonzero, else 0).
// This writes every byte of Q exactly once — no memset needed.
__global__ __launch_bounds__(256) void spde_fused(const float* __restrict__ kap,
                                                  const float* __restrict__ m,
                                                  const float* __restrict__ H,
                                                  float* __restrict__ Q) {
    const int oy[9] = {0, 0, 0, 1, -1, 1, 1, -1, -1};
    const int ox[9] = {0, 1, -1, 0, 0, 1, -1, 1, -1};

    int row = blockIdx.x;                 // 0 .. NB*NT*NN-1
    int b = row / (NT * NN);
    int g = row - b * (NT * NN);          // row within batch, 0..5119
    int t = g >> 10;
    int r = g & (NN - 1);
    int ry = r >> 5, rx = r & 31;
    int tid = threadIdx.x;

    // sk[d][ (dy+1)*3+(dx+1) ] : stencil of M[t] at neighbor node k_d of r
    // moff[z][ (dy+1)*3+(dx+1) ] : -M[t-1] row r (z=0) / -M[t+1] row r (z=1)
    // accL[ (dy+2)*5+(dx+2) ]  : row r of MM[t] (+I if interior t)
    __shared__ float sk[9][9];
    __shared__ float moff[2][9];
    __shared__ float accL[25];

    if (tid < 9) {
        int ky = ry + c_oy[tid], kx = rx + c_ox[tid];
        bool valid = ((unsigned)ky < NY) && ((unsigned)kx < NX);
        int k = valid ? (ky * NX + kx) : r;   // clamp; invalid path killed by sr==0
        float s[9];
        stencil9(kap, m, H, b, t, k, s);
#pragma unroll
        for (int e = 0; e < 9; ++e)
            sk[tid][(oy[e] + 1) * 3 + (ox[e] + 1)] = s[e];
    } else if (tid == 9) {
        float s[9] = {0,0,0,0,0,0,0,0,0};
        if (t >= 1) stencil9(kap, m, H, b, t - 1, r, s);
#pragma unroll
        for (int e = 0; e < 9; ++e)
            moff[0][(oy[e] + 1) * 3 + (ox[e] + 1)] = -s[e];
    } else if (tid == 10) {
        float s[9] = {0,0,0,0,0,0,0,0,0};
        if (t <= NT - 2) stencil9(kap, m, H, b, t + 1, r, s);
#pragma unroll
        for (int e = 0; e < 9; ++e)
            moff[1][(oy[e] + 1) * 3 + (ox[e] + 1)] = -s[e];
    }
    __syncthreads();

    if (tid < 25) {
        int dy = tid / 5 - 2, dx = tid % 5 - 2;
        float a = 0.f;
#pragma unroll
        for (int d1 = 0; d1 < 9; ++d1) {
            int dy2 = dy - oy[d1], dx2 = dx - ox[d1];
            if (dy2 >= -1 && dy2 <= 1 && dx2 >= -1 && dx2 <= 1) {
                // sr[d1] * (stencil at k_d1)[offset (dy2,dx2)]
                a += sk[0][(oy[d1] + 1) * 3 + (ox[d1] + 1)]
                   * sk[d1][(dy2 + 1) * 3 + (dx2 + 1)];
            }
        }
        if (tid == 12 && t >= 1 && t <= NT - 2) a += 1.0f;  // MM + I, interior t
        accL[tid] = a;
    }
    __syncthreads();

    // Stream the row: 1280 float4 slots, 5 per thread, coalesced.
    size_t base = ((size_t)b * QDIM + g) * QDIM;
#pragma unroll
    for (int kk = 0; kk < 5; ++kk) {
        int slot = tid + kk * 256;       // 0..1279
        int c0 = slot * 4;               // column of first element (16B aligned)
        int j  = c0 >> 10;               // time-block of these 4 cols (4 | 1024)
        int o  = c0 & (NN - 1);
        int dy = (o >> 5) - ry;          // constant across the 4 cols (4 | 32)
        int dx0 = (o & 31) - rx;
        float4 v = make_float4(0.f, 0.f, 0.f, 0.f);
        float* ve = &v.x;
        if (j == t) {
            if (dy >= -2 && dy <= 2) {
#pragma unroll
                for (int e = 0; e < 4; ++e) {
                    int dx = dx0 + e;
                    if (dx >= -2 && dx <= 2) ve[e] = accL[(dy + 2) * 5 + (dx + 2)];
                }
            }
        } else if ((j == t - 1 || j == t + 1) && dy >= -1 && dy <= 1) {
            int z = (j > t) ? 1 : 0;
#pragma unroll
            for (int e = 0; e < 4; ++e) {
                int dx = dx0 + e;
                if (dx >= -1 && dx <= 1) ve[e] = moff[z][(dy + 1) * 3 + (dx + 1)];
            }
        }
        *(float4*)(Q + base + c0) = v;
    }
}

extern "C" void kernel_launch(void* const* d_in, const int* in_sizes, int n_in,
                              void* d_out, int out_size, void* d_ws, size_t ws_size,
                              hipStream_t stream) {
    const float* kap = (const float*)d_in[0];
    const float* m   = (const float*)d_in[1];
    const float* H   = (const float*)d_in[2];
    float* Q = (float*)d_out;

    int nrows = NB * NT * NN;  // 20480 workgroups, one per output row
    spde_fused<<<nrows, 256, 0, stream>>>(kap, m, H, Q);
}